// Round 6
// baseline (307.285 us; speedup 1.0000x reference)
//
#include <hip/hip_runtime.h>

// Problem constants
#define NB 2
#define LL 2048
#define DD 1024
#define HH 16
#define NHH (NB*HH)          // 32 (n,h) pairs
#define LT (LL/64)           // 32 tiles of 64
#define KT16 (LL/16)         // 128 16-col tiles
#define CEXP 0.0450842200277801f   // log2(e)/32 : exp(x/32) == exp2(x*CEXP)

typedef __bf16 bf16x8 __attribute__((ext_vector_type(8)));
typedef unsigned short u16x8 __attribute__((ext_vector_type(8)));
typedef float f32x4 __attribute__((ext_vector_type(4)));

#define MFMA16 __builtin_amdgcn_mfma_f32_16x16x32_bf16
#define EXP2 __builtin_amdgcn_exp2f

__device__ __forceinline__ unsigned short f2bf(float f) {
    unsigned u = __float_as_uint(f);
    return (unsigned short)((u + 0x7fffu + ((u >> 16) & 1u)) >> 16);   // RNE
}
__device__ __forceinline__ float bf2f(unsigned short u) {
    return __uint_as_float(((unsigned)u) << 16);
}
__device__ __forceinline__ bf16x8 ldfrag(const unsigned short* p) {
    return *reinterpret_cast<const bf16x8*>(p);
}
// 8 consecutive fp32 -> bf16x8 fragment
__device__ __forceinline__ bf16x8 cvt8(const float* p) {
    float4 a = *reinterpret_cast<const float4*>(p);
    float4 b = *reinterpret_cast<const float4*>(p + 4);
    u16x8 u;
    u[0]=f2bf(a.x); u[1]=f2bf(a.y); u[2]=f2bf(a.z); u[3]=f2bf(a.w);
    u[4]=f2bf(b.x); u[5]=f2bf(b.y); u[6]=f2bf(b.z); u[7]=f2bf(b.w);
    return __builtin_bit_cast(bf16x8, u);
}
__device__ __forceinline__ ushort4 pack4(f32x4 d, float sc) {
    ushort4 o;
    o.x = f2bf(d[0]*sc); o.y = f2bf(d[1]*sc); o.z = f2bf(d[2]*sc); o.w = f2bf(d[3]*sc);
    return o;
}

// ---------------------------------------------------------------------------
// K1: projections via MFMA, TRANSPOSED operand roles: D = W(A) · X^T(B).
// C/D layout (col=lane&15=l, row=quad*4+r=d_out) makes each lane hold 4
// CONSECUTIVE d for one row l -> ushort4 (8B) packed stores, no LDS.
// Block = 64 rows x 1 head (grid 64 x 16 = 1024 blocks, 4/CU).
// qb is pre-scaled by log2(e)/32 so consumers exp2() the MFMA result raw.
// ---------------------------------------------------------------------------
__global__ __launch_bounds__(256) void proj_kernel(
    const float* __restrict__ values, const float* __restrict__ keys,
    const float* __restrict__ query,  const float* __restrict__ ovals,
    const float* __restrict__ okeys,  const float* __restrict__ Wv,
    const float* __restrict__ Wk,     const float* __restrict__ Wq,
    unsigned short* __restrict__ qb, unsigned short* __restrict__ okb,
    unsigned short* __restrict__ vb, unsigned short* __restrict__ ovb,
    float* __restrict__ ediag)
{
    const int t = threadIdx.x;
    const int w = t >> 6;
    const int lane = t & 63;
    const int n16 = lane & 15;
    const int quad = lane >> 4;
    const int h = blockIdx.y;
    const int row = blockIdx.x * 64 + w * 16 + n16;  // (n*L+l); == this lane's C-col
    const int nn = row >> 11;
    const int ll = row & 2047;
    const size_t xoff  = (size_t)row * DD + h * 64 + quad * 8;       // B-frag src
    const size_t qbase = (((size_t)(nn * HH + h)) * LL + ll) * 64;   // [nh][l][64]
    const size_t vbase = (size_t)row * DD + h * 64;                  // [row][1024]

    f32x4 ka[4];

    {   // ---- Wk phase: keys -> ka (kept in regs), okeys -> okb
        bf16x8 wa0[4], wa1[4];
#pragma unroll
        for (int mt = 0; mt < 4; ++mt) {
            const float* p = Wk + (mt * 16 + n16) * 64 + quad * 8;
            wa0[mt] = cvt8(p); wa1[mt] = cvt8(p + 32);
        }
        bf16x8 x0 = cvt8(keys + xoff), x1 = cvt8(keys + xoff + 32);
#pragma unroll
        for (int mt = 0; mt < 4; ++mt) {
            f32x4 d = {0.f,0.f,0.f,0.f};
            d = MFMA16(wa0[mt], x0, d, 0,0,0);
            ka[mt] = MFMA16(wa1[mt], x1, d, 0,0,0);
        }
        x0 = cvt8(okeys + xoff); x1 = cvt8(okeys + xoff + 32);
#pragma unroll
        for (int mt = 0; mt < 4; ++mt) {
            f32x4 d = {0.f,0.f,0.f,0.f};
            d = MFMA16(wa0[mt], x0, d, 0,0,0);
            d = MFMA16(wa1[mt], x1, d, 0,0,0);
            *reinterpret_cast<ushort4*>(okb + qbase + mt*16 + quad*4) = pack4(d, 1.0f);
        }
    }
    {   // ---- Wq phase: query -> qb (scaled), ediag from qa·ka (fp32)
        bf16x8 wa0[4], wa1[4];
#pragma unroll
        for (int mt = 0; mt < 4; ++mt) {
            const float* p = Wq + (mt * 16 + n16) * 64 + quad * 8;
            wa0[mt] = cvt8(p); wa1[mt] = cvt8(p + 32);
        }
        bf16x8 x0 = cvt8(query + xoff), x1 = cvt8(query + xoff + 32);
        f32x4 qa[4];
#pragma unroll
        for (int mt = 0; mt < 4; ++mt) {
            f32x4 d = {0.f,0.f,0.f,0.f};
            d = MFMA16(wa0[mt], x0, d, 0,0,0);
            qa[mt] = MFMA16(wa1[mt], x1, d, 0,0,0);
            *reinterpret_cast<ushort4*>(qb + qbase + mt*16 + quad*4) = pack4(qa[mt], CEXP);
        }
        float p = 0.f;
#pragma unroll
        for (int mt = 0; mt < 4; ++mt)
            p += qa[mt][0]*ka[mt][0] + qa[mt][1]*ka[mt][1]
               + qa[mt][2]*ka[mt][2] + qa[mt][3]*ka[mt][3];
        p += __shfl_xor(p, 16);
        p += __shfl_xor(p, 32);
        if (lane < 16)
            ediag[((size_t)(nn * HH + h)) * LL + ll] = p;
    }
    {   // ---- Wv phase: values -> vb, origin_values -> ovb
        bf16x8 wa0[4], wa1[4];
#pragma unroll
        for (int mt = 0; mt < 4; ++mt) {
            const float* p = Wv + (mt * 16 + n16) * 64 + quad * 8;
            wa0[mt] = cvt8(p); wa1[mt] = cvt8(p + 32);
        }
        bf16x8 x0 = cvt8(values + xoff), x1 = cvt8(values + xoff + 32);
#pragma unroll
        for (int mt = 0; mt < 4; ++mt) {
            f32x4 d = {0.f,0.f,0.f,0.f};
            d = MFMA16(wa0[mt], x0, d, 0,0,0);
            d = MFMA16(wa1[mt], x1, d, 0,0,0);
            *reinterpret_cast<ushort4*>(vb + vbase + mt*16 + quad*4) = pack4(d, 1.0f);
        }
        x0 = cvt8(ovals + xoff); x1 = cvt8(ovals + xoff + 32);
#pragma unroll
        for (int mt = 0; mt < 4; ++mt) {
            f32x4 d = {0.f,0.f,0.f,0.f};
            d = MFMA16(wa0[mt], x0, d, 0,0,0);
            d = MFMA16(wa1[mt], x1, d, 0,0,0);
            *reinterpret_cast<ushort4*>(ovb + vbase + mt*16 + quad*4) = pack4(d, 1.0f);
        }
    }
}

// ---------------------------------------------------------------------------
// K2: partial row-sums of exp(E/32) via MFMA, load-balanced.
// qb is pre-scaled so exp(e/32) == exp2(raw MFMA result).
// ---------------------------------------------------------------------------
__global__ __launch_bounds__(256) void zrow_part(
    const unsigned short* __restrict__ qb, const unsigned short* __restrict__ okb,
    float* __restrict__ Zbuf)
{
    const int px = blockIdx.x;
    const int pair = px >> 2;
    const int s = px & 3;
    const int nh = blockIdx.y;
    const int t = threadIdx.x;
    const int w = t >> 6;
    const int lane = t & 63;
    const int n = lane & 15;
    const int quad = lane >> 4;
    const size_t base = (size_t)nh * (LL * 64);
    const size_t nhL = (size_t)nh * LL;
    const int r0 = 4 * s + w;     // k-tile residue 0..15

#pragma unroll
    for (int half = 0; half < 2; ++half) {
        const int qt = half ? (31 - pair) : pair;
        const int kend = 4 * qt + 4;

        bf16x8 aq[4][2];
#pragma unroll
        for (int rt = 0; rt < 4; ++rt) {
            const unsigned short* p = qb + base + (size_t)(qt*64 + rt*16 + n) * 64 + quad * 8;
            aq[rt][0] = ldfrag(p); aq[rt][1] = ldfrag(p + 32);
        }

        float zacc[4][4];
#pragma unroll
        for (int rt = 0; rt < 4; ++rt)
#pragma unroll
            for (int r = 0; r < 4; ++r) zacc[rt][r] = 0.f;

        bf16x8 b0c, b1c;
        if (r0 < kend) {
            const unsigned short* kp = okb + base + (size_t)(r0*16 + n) * 64 + quad * 8;
            b0c = ldfrag(kp); b1c = ldfrag(kp + 32);
        }
        for (int kt = r0; kt < kend; kt += 16) {
            bf16x8 b0 = b0c, b1 = b1c;
            if (kt + 16 < kend) {
                const unsigned short* kp = okb + base + (size_t)((kt+16)*16 + n) * 64 + quad * 8;
                b0c = ldfrag(kp); b1c = ldfrag(kp + 32);
            }
            const int dk = kt - 4*qt;   // <0: all row-tiles full
#pragma unroll
            for (int rt = 0; rt < 4; ++rt) {
                if (rt < dk) continue;                    // fully masked
                f32x4 d = {0.f,0.f,0.f,0.f};
                d = MFMA16(aq[rt][0], b0, d, 0,0,0);
                d = MFMA16(aq[rt][1], b1, d, 0,0,0);
                if (rt == dk) {                            // diagonal tile
#pragma unroll
                    for (int r = 0; r < 4; ++r)
                        if (n < quad*4 + r) zacc[rt][r] += EXP2(d[r]);
                } else {
#pragma unroll
                    for (int r = 0; r < 4; ++r) zacc[rt][r] += EXP2(d[r]);
                }
            }
        }

        // reduce over the 16 col lanes of each quad, then one atomic per row
#pragma unroll
        for (int rt = 0; rt < 4; ++rt)
#pragma unroll
            for (int r = 0; r < 4; ++r) {
                float z = zacc[rt][r];
                z += __shfl_xor(z, 1); z += __shfl_xor(z, 2);
                z += __shfl_xor(z, 4); z += __shfl_xor(z, 8);
                if (n == 0)
                    atomicAdd(&Zbuf[nhL + qt*64 + rt*16 + quad*4 + r], z);
            }
    }
}

// ---------------------------------------------------------------------------
// K2b: finalize invZ and diag_s from Zbuf + ediag.
// ---------------------------------------------------------------------------
__global__ __launch_bounds__(256) void zfin_kernel(
    const float* __restrict__ Zbuf, const float* __restrict__ ediag,
    float* __restrict__ invZ, float* __restrict__ diag_s)
{
    const int i = blockIdx.x * 256 + threadIdx.x;
    const float de = EXP2(ediag[i] * CEXP);
    const float iz = 1.f / (Zbuf[i] + de);
    invZ[i]   = iz;
    diag_s[i] = de * iz;
}

// ---------------------------------------------------------------------------
// K3: partial colsum[l] = sum_{q>l} exp(e[q,l]/32)*invZ[q], load-balanced.
// ---------------------------------------------------------------------------
__global__ __launch_bounds__(256) void colsum_part(
    const unsigned short* __restrict__ qb, const unsigned short* __restrict__ okb,
    const float* __restrict__ invZ, float* __restrict__ colsum)
{
    const int px = blockIdx.x;
    const int pair = px >> 2;
    const int s = px & 3;
    const int nh = blockIdx.y;
    const int t = threadIdx.x;
    const int w = t >> 6;
    const int lane = t & 63;
    const int n = lane & 15;
    const int quad = lane >> 4;
    const size_t base = (size_t)nh * (LL * 64);
    const size_t nhL = (size_t)nh * LL;
    const int r0 = 4 * s + w;     // residue 0..15

#pragma unroll
    for (int half = 0; half < 2; ++half) {
        const int lt = half ? (31 - pair) : pair;

        bf16x8 bl[4][2];
#pragma unroll
        for (int ct = 0; ct < 4; ++ct) {
            const unsigned short* p = okb + base + (size_t)(lt*64 + ct*16 + n) * 64 + quad * 8;
            bl[ct][0] = ldfrag(p); bl[ct][1] = ldfrag(p + 32);
        }

        float cacc[4] = {0.f, 0.f, 0.f, 0.f};

        const int kstart = 4*lt + r0;
        bf16x8 a0c, a1c; float izc = 0.f;
        if (kstart < KT16) {
            const unsigned short* qp = qb + base + (size_t)(kstart*16 + n) * 64 + quad * 8;
            a0c = ldfrag(qp); a1c = ldfrag(qp + 32);
            izc = invZ[nhL + kstart*16 + n];
        }
        for (int kt = kstart; kt < KT16; kt += 16) {
            bf16x8 a0 = a0c, a1 = a1c; const float izq = izc;
            if (kt + 16 < KT16) {
                const unsigned short* qp = qb + base + (size_t)((kt+16)*16 + n) * 64 + quad * 8;
                a0c = ldfrag(qp); a1c = ldfrag(qp + 32);
                izc = invZ[nhL + (kt+16)*16 + n];
            }
            float izr[4];
#pragma unroll
            for (int r = 0; r < 4; ++r) izr[r] = __shfl(izq, quad*4 + r);
            const int dk = kt - 4*lt;   // >=0 by construction
#pragma unroll
            for (int ct = 0; ct < 4; ++ct) {
                if (ct > dk) continue;                    // empty (q < l)
                f32x4 d = {0.f,0.f,0.f,0.f};
                d = MFMA16(a0, bl[ct][0], d, 0,0,0);
                d = MFMA16(a1, bl[ct][1], d, 0,0,0);
                if (ct == dk) {                            // diagonal tile: q>l only
#pragma unroll
                    for (int r = 0; r < 4; ++r)
                        if (quad*4 + r > n) cacc[ct] += EXP2(d[r]) * izr[r];
                } else {
#pragma unroll
                    for (int r = 0; r < 4; ++r) cacc[ct] += EXP2(d[r]) * izr[r];
                }
            }
        }

#pragma unroll
        for (int ct = 0; ct < 4; ++ct) {
            float c = cacc[ct];
            c += __shfl_down(c, 32);
            c += __shfl_down(c, 16);
            if (lane < 16)
                atomicAdd(&colsum[nhL + lt*64 + ct*16 + lane], c);
        }
    }
}

// ---------------------------------------------------------------------------
// K4: fc_w -> bf16
// ---------------------------------------------------------------------------
__global__ __launch_bounds__(256) void fcw_kernel(
    const float* __restrict__ fc_w, unsigned short* __restrict__ fcwb)
{
    const int idx = blockIdx.x * 1024 + threadIdx.x * 4;
    float4 wv = *reinterpret_cast<const float4*>(fc_w + idx);
    ushort4 o;
    o.x = f2bf(wv.x); o.y = f2bf(wv.y); o.z = f2bf(wv.z); o.w = f2bf(wv.w);
    *reinterpret_cast<ushort4*>(fcwb + idx) = o;
}

// ---------------------------------------------------------------------------
// K5: attb[row][d] = bf16( diag_s*vb + colsum*ovb )
// ---------------------------------------------------------------------------
__global__ __launch_bounds__(256) void att_kernel(
    const unsigned short* __restrict__ vb, const unsigned short* __restrict__ ovb,
    const float* __restrict__ diag_s, const float* __restrict__ colsum,
    unsigned short* __restrict__ attb)
{
    const int row = blockIdx.x;            // n*L + l
    const int nn = row >> 11, l = row & 2047;
    const int t = threadIdx.x;
    const int d0 = t * 4;
    const int h = t >> 4;                  // d0>>6
    const size_t nhl = ((size_t)(nn * HH + h)) * LL + l;
    const float ds = diag_s[nhl];
    const float cs = colsum[nhl];
    const ushort4 v  = *reinterpret_cast<const ushort4*>(vb  + (size_t)row * DD + d0);
    const ushort4 ov = *reinterpret_cast<const ushort4*>(ovb + (size_t)row * DD + d0);
    ushort4 o;
    o.x = f2bf(ds * bf2f(v.x) + cs * bf2f(ov.x));
    o.y = f2bf(ds * bf2f(v.y) + cs * bf2f(ov.y));
    o.z = f2bf(ds * bf2f(v.z) + cs * bf2f(ov.z));
    o.w = f2bf(ds * bf2f(v.w) + cs * bf2f(ov.w));
    *reinterpret_cast<ushort4*>(attb + (size_t)row * DD + d0) = o;
}

// ---------------------------------------------------------------------------
// K6: out = attb @ fcwb^T + fc_b, bf16 MFMA GEMM, register-pipelined.
// ---------------------------------------------------------------------------
__global__ __launch_bounds__(256) void out_kernel(
    const unsigned short* __restrict__ attb, const unsigned short* __restrict__ fcwb,
    const float* __restrict__ fc_b, float* __restrict__ out)
{
    const int ct = blockIdx.x;   // 0..15  col tile (64 cols)
    const int rt = blockIdx.y;   // 0..31  row tile (128 rows)
    const int t = threadIdx.x;
    const int w = t >> 6;
    const int lane = t & 63;
    const int n = lane & 15;
    const int quad = lane >> 4;

    const int row0 = rt * 128 + w * 32;
    const int col0 = ct * 64;

    const unsigned short* ap = attb + (size_t)(row0 + n) * DD + quad * 8;
    const unsigned short* bp = fcwb + (size_t)(col0 + n) * DD + quad * 8;

    f32x4 acc[2][4];
#pragma unroll
    for (int i = 0; i < 2; ++i)
#pragma unroll
        for (int j = 0; j < 4; ++j) acc[i][j] = (f32x4){0.f, 0.f, 0.f, 0.f};

    bf16x8 a[2][2], b[2][4];
    a[0][0] = ldfrag(ap);
    a[0][1] = ldfrag(ap + 16 * DD);
#pragma unroll
    for (int j = 0; j < 4; ++j) b[0][j] = ldfrag(bp + (size_t)(j * 16) * DD);

    int cur = 0;
    for (int kc = 0; kc < DD; kc += 32) {
        const int nxt = cur ^ 1;
        if (kc + 32 < DD) {
            a[nxt][0] = ldfrag(ap + kc + 32);
            a[nxt][1] = ldfrag(ap + 16 * DD + kc + 32);
#pragma unroll
            for (int j = 0; j < 4; ++j)
                b[nxt][j] = ldfrag(bp + (size_t)(j * 16) * DD + kc + 32);
        }
#pragma unroll
        for (int i = 0; i < 2; ++i)
#pragma unroll
            for (int j = 0; j < 4; ++j)
                acc[i][j] = MFMA16(a[cur][i], b[cur][j], acc[i][j], 0, 0, 0);
        cur = nxt;
    }

#pragma unroll
    for (int j = 0; j < 4; ++j) {
        const int col = col0 + j * 16 + n;
        const float bias = fc_b[col];
#pragma unroll
        for (int i = 0; i < 2; ++i)
#pragma unroll
            for (int r = 0; r < 4; ++r) {
                const int grow = row0 + i * 16 + quad * 4 + r;
                out[(size_t)grow * DD + col] = acc[i][j][r] + bias;
            }
    }
}

// ---------------------------------------------------------------------------
extern "C" void kernel_launch(void* const* d_in, const int* in_sizes, int n_in,
                              void* d_out, int out_size, void* d_ws, size_t ws_size,
                              hipStream_t stream) {
    const float* values = (const float*)d_in[0];
    const float* keys   = (const float*)d_in[1];
    const float* query  = (const float*)d_in[2];
    const float* ovals  = (const float*)d_in[3];
    const float* okeys  = (const float*)d_in[4];
    const float* Wv     = (const float*)d_in[5];
    const float* Wk     = (const float*)d_in[6];
    const float* Wq     = (const float*)d_in[7];
    const float* fc_w   = (const float*)d_in[8];
    const float* fc_b   = (const float*)d_in[9];
    // d_in[10]: mask — HIST==L makes it pure causal, handled analytically.
    float* out = (float*)d_out;

    float* ws      = (float*)d_ws;
    float* ediag   = ws;                     // 65536 f32
    float* Zbuf    = ediag + 65536;          // 65536 f32 (atomic accum)
    float* colsum  = Zbuf + 65536;           // 65536 f32 (atomic accum)
    float* invZ    = colsum + 65536;
    float* diag_s  = invZ + 65536;
    unsigned short* qb   = (unsigned short*)(diag_s + 65536);  // [32][2048][64] bf16
    unsigned short* okb  = qb   + 4194304;
    unsigned short* vb   = okb  + 4194304;   // [n][l][1024] bf16
    unsigned short* ovb  = vb   + 4194304;
    unsigned short* attb = ovb  + 4194304;   // [4096][1024] bf16
    unsigned short* fcwb = attb + 4194304;   // [1024][1024] bf16

    // zero the two atomic accumulators (Zbuf, colsum are adjacent)
    hipMemsetAsync(Zbuf, 0, 2 * 65536 * sizeof(float), stream);

    proj_kernel<<<dim3(64, 16), 256, 0, stream>>>(
        values, keys, query, ovals, okeys, Wv, Wk, Wq, qb, okb, vb, ovb, ediag);
    fcw_kernel<<<dim3(1024), 256, 0, stream>>>(fc_w, fcwb);
    zrow_part<<<dim3(64, NHH), 256, 0, stream>>>(qb, okb, Zbuf);
    zfin_kernel<<<dim3(256), 256, 0, stream>>>(Zbuf, ediag, invZ, diag_s);
    colsum_part<<<dim3(64, NHH), 256, 0, stream>>>(qb, okb, invZ, colsum);
    att_kernel<<<dim3(NB * LL), 256, 0, stream>>>(vb, ovb, diag_s, colsum, attb);
    out_kernel<<<dim3(16, 32), 256, 0, stream>>>(attb, fcwb, fc_b, out);
}

// Round 7
// 293.752 us; speedup vs baseline: 1.0461x; 1.0461x over previous
//
#include <hip/hip_runtime.h>

// Problem constants
#define NB 2
#define LL 2048
#define DD 1024
#define HH 16
#define NHH (NB*HH)          // 32 (n,h) pairs
#define LT (LL/64)           // 32 tiles of 64
#define KT16 (LL/16)         // 128 16-col tiles
#define CEXP 0.0450842200277801f   // log2(e)/32 : exp(x/32) == exp2(x*CEXP)

typedef __bf16 bf16x8 __attribute__((ext_vector_type(8)));
typedef unsigned short u16x8 __attribute__((ext_vector_type(8)));
typedef float f32x4 __attribute__((ext_vector_type(4)));

#define MFMA16 __builtin_amdgcn_mfma_f32_16x16x32_bf16
#define EXP2 __builtin_amdgcn_exp2f

__device__ __forceinline__ unsigned short f2bf(float f) {
    unsigned u = __float_as_uint(f);
    return (unsigned short)((u + 0x7fffu + ((u >> 16) & 1u)) >> 16);   // RNE
}
__device__ __forceinline__ float bf2f(unsigned short u) {
    return __uint_as_float(((unsigned)u) << 16);
}
__device__ __forceinline__ bf16x8 ldfrag(const unsigned short* p) {
    return *reinterpret_cast<const bf16x8*>(p);
}
__device__ __forceinline__ bf16x8 cvt8v(float4 a, float4 b) {
    u16x8 u;
    u[0]=f2bf(a.x); u[1]=f2bf(a.y); u[2]=f2bf(a.z); u[3]=f2bf(a.w);
    u[4]=f2bf(b.x); u[5]=f2bf(b.y); u[6]=f2bf(b.z); u[7]=f2bf(b.w);
    return __builtin_bit_cast(bf16x8, u);
}
__device__ __forceinline__ ushort4 pack4(f32x4 d, float sc) {
    ushort4 o;
    o.x = f2bf(d[0]*sc); o.y = f2bf(d[1]*sc); o.z = f2bf(d[2]*sc); o.w = f2bf(d[3]*sc);
    return o;
}

// ---------------------------------------------------------------------------
// K0: pre-convert Wk,Wq,Wv (fp32 64x64) into bf16 MFMA A-frags in the exact
// per-lane layout proj consumes: wfrag[(m*8+f)*64+lane][8], f = mt*2+half,
// frag content = W[(mt*16+n16)*64 + quad*8 + half*32 .. +8].
// ---------------------------------------------------------------------------
__global__ __launch_bounds__(256) void wcvt_kernel(
    const float* __restrict__ Wk, const float* __restrict__ Wq,
    const float* __restrict__ Wv, unsigned short* __restrict__ wfrag)
{
    const int s = blockIdx.x * 256 + threadIdx.x;   // 0..1535
    const int m = s >> 9;
    const int rem = s & 511;
    const int f = rem >> 6;
    const int lane = rem & 63;
    const int n16 = lane & 15, quad = lane >> 4;
    const int mt = f >> 1, half = f & 1;
    const float* W = (m == 0) ? Wk : (m == 1) ? Wq : Wv;
    const float* p = W + (mt*16 + n16)*64 + quad*8 + half*32;
    float4 a = *reinterpret_cast<const float4*>(p);
    float4 b = *reinterpret_cast<const float4*>(p + 4);
    *reinterpret_cast<bf16x8*>(wfrag + (size_t)s * 8) = cvt8v(a, b);
}

// ---------------------------------------------------------------------------
// K1: projections via MFMA, D = W(A) . X^T(B); C/D lane layout gives each
// lane 4 consecutive d for one row l -> 8B packed stores. Grid (64,16,2):
// z=0 handles keys/query/okeys (Wk,Wq) + ediag; z=1 values/ovals (Wv).
// All global loads are issued up front (independent) to maximize MLP;
// W comes pre-converted from wfrag (L2-hot, no per-block cvt VALU).
// qb is pre-scaled by log2(e)/32 so consumers exp2() raw MFMA results.
// ---------------------------------------------------------------------------
__global__ __launch_bounds__(256) void proj_kernel(
    const float* __restrict__ values, const float* __restrict__ keys,
    const float* __restrict__ query,  const float* __restrict__ ovals,
    const float* __restrict__ okeys,  const unsigned short* __restrict__ wfrag,
    unsigned short* __restrict__ qb, unsigned short* __restrict__ okb,
    unsigned short* __restrict__ vb, unsigned short* __restrict__ ovb,
    float* __restrict__ ediag)
{
    const int t = threadIdx.x;
    const int w = t >> 6;
    const int lane = t & 63;
    const int n16 = lane & 15;
    const int quad = lane >> 4;
    const int h = blockIdx.y;
    const int row = blockIdx.x * 64 + w * 16 + n16;  // (n*L+l) == this lane's C-col
    const int nn = row >> 11;
    const int ll = row & 2047;
    const size_t xoff  = (size_t)row * DD + h * 64 + quad * 8;       // B-frag src
    const size_t qbase = (((size_t)(nn * HH + h)) * LL + ll) * 64;   // [nh][l][64]
    const size_t vbase = (size_t)row * DD + h * 64;                  // [row][1024]

    if (blockIdx.z == 0) {
        // ---- issue ALL loads first (independent) ----
        const float4* kp = reinterpret_cast<const float4*>(keys  + xoff);
        const float4* qp = reinterpret_cast<const float4*>(query + xoff);
        const float4* op = reinterpret_cast<const float4*>(okeys + xoff);
        float4 k0 = kp[0], k1 = kp[1], k2 = kp[8], k3 = kp[9];   // +0,+4,+32,+36
        float4 q0 = qp[0], q1 = qp[1], q2 = qp[8], q3 = qp[9];
        float4 o0 = op[0], o1 = op[1], o2 = op[8], o3 = op[9];
        bf16x8 wk[8], wq[8];
#pragma unroll
        for (int f = 0; f < 8; ++f) {
            wk[f] = ldfrag(wfrag + (size_t)(f * 64 + lane) * 8);
            wq[f] = ldfrag(wfrag + (size_t)((8 + f) * 64 + lane) * 8);
        }
        // ---- convert ----
        bf16x8 xk0 = cvt8v(k0, k1), xk1 = cvt8v(k2, k3);
        bf16x8 xq0 = cvt8v(q0, q1), xq1 = cvt8v(q2, q3);
        bf16x8 xo0 = cvt8v(o0, o1), xo1 = cvt8v(o2, o3);
        // ---- MFMA ----
        f32x4 ka[4], qa[4];
#pragma unroll
        for (int mt = 0; mt < 4; ++mt) {
            f32x4 d = {0.f,0.f,0.f,0.f};
            d = MFMA16(wk[mt*2], xk0, d, 0,0,0);
            ka[mt] = MFMA16(wk[mt*2+1], xk1, d, 0,0,0);
        }
#pragma unroll
        for (int mt = 0; mt < 4; ++mt) {
            f32x4 d = {0.f,0.f,0.f,0.f};
            d = MFMA16(wq[mt*2], xq0, d, 0,0,0);
            qa[mt] = MFMA16(wq[mt*2+1], xq1, d, 0,0,0);
            *reinterpret_cast<ushort4*>(qb + qbase + mt*16 + quad*4) = pack4(qa[mt], CEXP);
        }
#pragma unroll
        for (int mt = 0; mt < 4; ++mt) {
            f32x4 d = {0.f,0.f,0.f,0.f};
            d = MFMA16(wk[mt*2], xo0, d, 0,0,0);
            d = MFMA16(wk[mt*2+1], xo1, d, 0,0,0);
            *reinterpret_cast<ushort4*>(okb + qbase + mt*16 + quad*4) = pack4(d, 1.0f);
        }
        // ediag[l] = sum_d q*k (fp32)
        float p = 0.f;
#pragma unroll
        for (int mt = 0; mt < 4; ++mt)
            p += qa[mt][0]*ka[mt][0] + qa[mt][1]*ka[mt][1]
               + qa[mt][2]*ka[mt][2] + qa[mt][3]*ka[mt][3];
        p += __shfl_xor(p, 16);
        p += __shfl_xor(p, 32);
        if (lane < 16)
            ediag[((size_t)(nn * HH + h)) * LL + ll] = p;
    } else {
        const float4* vp = reinterpret_cast<const float4*>(values + xoff);
        const float4* op = reinterpret_cast<const float4*>(ovals  + xoff);
        float4 v0 = vp[0], v1 = vp[1], v2 = vp[8], v3 = vp[9];
        float4 o0 = op[0], o1 = op[1], o2 = op[8], o3 = op[9];
        bf16x8 wv[8];
#pragma unroll
        for (int f = 0; f < 8; ++f)
            wv[f] = ldfrag(wfrag + (size_t)((16 + f) * 64 + lane) * 8);
        bf16x8 xv0 = cvt8v(v0, v1), xv1 = cvt8v(v2, v3);
        bf16x8 xo0 = cvt8v(o0, o1), xo1 = cvt8v(o2, o3);
#pragma unroll
        for (int mt = 0; mt < 4; ++mt) {
            f32x4 d = {0.f,0.f,0.f,0.f};
            d = MFMA16(wv[mt*2], xv0, d, 0,0,0);
            d = MFMA16(wv[mt*2+1], xv1, d, 0,0,0);
            *reinterpret_cast<ushort4*>(vb + vbase + mt*16 + quad*4) = pack4(d, 1.0f);
        }
#pragma unroll
        for (int mt = 0; mt < 4; ++mt) {
            f32x4 d = {0.f,0.f,0.f,0.f};
            d = MFMA16(wv[mt*2], xo0, d, 0,0,0);
            d = MFMA16(wv[mt*2+1], xo1, d, 0,0,0);
            *reinterpret_cast<ushort4*>(ovb + vbase + mt*16 + quad*4) = pack4(d, 1.0f);
        }
    }
}

// ---------------------------------------------------------------------------
// K2: partial row-sums of exp(E/32) via MFMA, load-balanced.
// qb is pre-scaled so exp(e/32) == exp2(raw MFMA result).
// ---------------------------------------------------------------------------
__global__ __launch_bounds__(256) void zrow_part(
    const unsigned short* __restrict__ qb, const unsigned short* __restrict__ okb,
    float* __restrict__ Zbuf)
{
    const int px = blockIdx.x;
    const int pair = px >> 2;
    const int s = px & 3;
    const int nh = blockIdx.y;
    const int t = threadIdx.x;
    const int w = t >> 6;
    const int lane = t & 63;
    const int n = lane & 15;
    const int quad = lane >> 4;
    const size_t base = (size_t)nh * (LL * 64);
    const size_t nhL = (size_t)nh * LL;
    const int r0 = 4 * s + w;     // k-tile residue 0..15

#pragma unroll
    for (int half = 0; half < 2; ++half) {
        const int qt = half ? (31 - pair) : pair;
        const int kend = 4 * qt + 4;

        bf16x8 aq[4][2];
#pragma unroll
        for (int rt = 0; rt < 4; ++rt) {
            const unsigned short* p = qb + base + (size_t)(qt*64 + rt*16 + n) * 64 + quad * 8;
            aq[rt][0] = ldfrag(p); aq[rt][1] = ldfrag(p + 32);
        }

        float zacc[4][4];
#pragma unroll
        for (int rt = 0; rt < 4; ++rt)
#pragma unroll
            for (int r = 0; r < 4; ++r) zacc[rt][r] = 0.f;

        bf16x8 b0c, b1c;
        if (r0 < kend) {
            const unsigned short* kp = okb + base + (size_t)(r0*16 + n) * 64 + quad * 8;
            b0c = ldfrag(kp); b1c = ldfrag(kp + 32);
        }
        for (int kt = r0; kt < kend; kt += 16) {
            bf16x8 b0 = b0c, b1 = b1c;
            if (kt + 16 < kend) {
                const unsigned short* kp = okb + base + (size_t)((kt+16)*16 + n) * 64 + quad * 8;
                b0c = ldfrag(kp); b1c = ldfrag(kp + 32);
            }
            const int dk = kt - 4*qt;   // <0: all row-tiles full
#pragma unroll
            for (int rt = 0; rt < 4; ++rt) {
                if (rt < dk) continue;                    // fully masked
                f32x4 d = {0.f,0.f,0.f,0.f};
                d = MFMA16(aq[rt][0], b0, d, 0,0,0);
                d = MFMA16(aq[rt][1], b1, d, 0,0,0);
                if (rt == dk) {                            // diagonal tile
#pragma unroll
                    for (int r = 0; r < 4; ++r)
                        if (n < quad*4 + r) zacc[rt][r] += EXP2(d[r]);
                } else {
#pragma unroll
                    for (int r = 0; r < 4; ++r) zacc[rt][r] += EXP2(d[r]);
                }
            }
        }

        // reduce over the 16 col lanes of each quad, then one atomic per row
#pragma unroll
        for (int rt = 0; rt < 4; ++rt)
#pragma unroll
            for (int r = 0; r < 4; ++r) {
                float z = zacc[rt][r];
                z += __shfl_xor(z, 1); z += __shfl_xor(z, 2);
                z += __shfl_xor(z, 4); z += __shfl_xor(z, 8);
                if (n == 0)
                    atomicAdd(&Zbuf[nhL + qt*64 + rt*16 + quad*4 + r], z);
            }
    }
}

// ---------------------------------------------------------------------------
// K2b: finalize invZ and diag_s from Zbuf + ediag.
// ---------------------------------------------------------------------------
__global__ __launch_bounds__(256) void zfin_kernel(
    const float* __restrict__ Zbuf, const float* __restrict__ ediag,
    float* __restrict__ invZ, float* __restrict__ diag_s)
{
    const int i = blockIdx.x * 256 + threadIdx.x;
    const float de = EXP2(ediag[i] * CEXP);
    const float iz = 1.f / (Zbuf[i] + de);
    invZ[i]   = iz;
    diag_s[i] = de * iz;
}

// ---------------------------------------------------------------------------
// K3: partial colsum[l] = sum_{q>l} exp(e[q,l]/32)*invZ[q], load-balanced.
// ---------------------------------------------------------------------------
__global__ __launch_bounds__(256) void colsum_part(
    const unsigned short* __restrict__ qb, const unsigned short* __restrict__ okb,
    const float* __restrict__ invZ, float* __restrict__ colsum)
{
    const int px = blockIdx.x;
    const int pair = px >> 2;
    const int s = px & 3;
    const int nh = blockIdx.y;
    const int t = threadIdx.x;
    const int w = t >> 6;
    const int lane = t & 63;
    const int n = lane & 15;
    const int quad = lane >> 4;
    const size_t base = (size_t)nh * (LL * 64);
    const size_t nhL = (size_t)nh * LL;
    const int r0 = 4 * s + w;     // residue 0..15

#pragma unroll
    for (int half = 0; half < 2; ++half) {
        const int lt = half ? (31 - pair) : pair;

        bf16x8 bl[4][2];
#pragma unroll
        for (int ct = 0; ct < 4; ++ct) {
            const unsigned short* p = okb + base + (size_t)(lt*64 + ct*16 + n) * 64 + quad * 8;
            bl[ct][0] = ldfrag(p); bl[ct][1] = ldfrag(p + 32);
        }

        float cacc[4] = {0.f, 0.f, 0.f, 0.f};

        const int kstart = 4*lt + r0;
        bf16x8 a0c, a1c; float izc = 0.f;
        if (kstart < KT16) {
            const unsigned short* qp = qb + base + (size_t)(kstart*16 + n) * 64 + quad * 8;
            a0c = ldfrag(qp); a1c = ldfrag(qp + 32);
            izc = invZ[nhL + kstart*16 + n];
        }
        for (int kt = kstart; kt < KT16; kt += 16) {
            bf16x8 a0 = a0c, a1 = a1c; const float izq = izc;
            if (kt + 16 < KT16) {
                const unsigned short* qp = qb + base + (size_t)((kt+16)*16 + n) * 64 + quad * 8;
                a0c = ldfrag(qp); a1c = ldfrag(qp + 32);
                izc = invZ[nhL + (kt+16)*16 + n];
            }
            float izr[4];
#pragma unroll
            for (int r = 0; r < 4; ++r) izr[r] = __shfl(izq, quad*4 + r);
            const int dk = kt - 4*lt;   // >=0 by construction
#pragma unroll
            for (int ct = 0; ct < 4; ++ct) {
                if (ct > dk) continue;                    // empty (q < l)
                f32x4 d = {0.f,0.f,0.f,0.f};
                d = MFMA16(a0, bl[ct][0], d, 0,0,0);
                d = MFMA16(a1, bl[ct][1], d, 0,0,0);
                if (ct == dk) {                            // diagonal tile: q>l only
#pragma unroll
                    for (int r = 0; r < 4; ++r)
                        if (quad*4 + r > n) cacc[ct] += EXP2(d[r]) * izr[r];
                } else {
#pragma unroll
                    for (int r = 0; r < 4; ++r) cacc[ct] += EXP2(d[r]) * izr[r];
                }
            }
        }

#pragma unroll
        for (int ct = 0; ct < 4; ++ct) {
            float c = cacc[ct];
            c += __shfl_down(c, 32);
            c += __shfl_down(c, 16);
            if (lane < 16)
                atomicAdd(&colsum[nhL + lt*64 + ct*16 + lane], c);
        }
    }
}

// ---------------------------------------------------------------------------
// K4: fc_w -> bf16
// ---------------------------------------------------------------------------
__global__ __launch_bounds__(256) void fcw_kernel(
    const float* __restrict__ fc_w, unsigned short* __restrict__ fcwb)
{
    const int idx = blockIdx.x * 1024 + threadIdx.x * 4;
    float4 wv = *reinterpret_cast<const float4*>(fc_w + idx);
    ushort4 o;
    o.x = f2bf(wv.x); o.y = f2bf(wv.y); o.z = f2bf(wv.z); o.w = f2bf(wv.w);
    *reinterpret_cast<ushort4*>(fcwb + idx) = o;
}

// ---------------------------------------------------------------------------
// K5: attb[row][d] = bf16( diag_s*vb + colsum*ovb )
// ---------------------------------------------------------------------------
__global__ __launch_bounds__(256) void att_kernel(
    const unsigned short* __restrict__ vb, const unsigned short* __restrict__ ovb,
    const float* __restrict__ diag_s, const float* __restrict__ colsum,
    unsigned short* __restrict__ attb)
{
    const int row = blockIdx.x;            // n*L + l
    const int nn = row >> 11, l = row & 2047;
    const int t = threadIdx.x;
    const int d0 = t * 4;
    const int h = t >> 4;                  // d0>>6
    const size_t nhl = ((size_t)(nn * HH + h)) * LL + l;
    const float ds = diag_s[nhl];
    const float cs = colsum[nhl];
    const ushort4 v  = *reinterpret_cast<const ushort4*>(vb  + (size_t)row * DD + d0);
    const ushort4 ov = *reinterpret_cast<const ushort4*>(ovb + (size_t)row * DD + d0);
    ushort4 o;
    o.x = f2bf(ds * bf2f(v.x) + cs * bf2f(ov.x));
    o.y = f2bf(ds * bf2f(v.y) + cs * bf2f(ov.y));
    o.z = f2bf(ds * bf2f(v.z) + cs * bf2f(ov.z));
    o.w = f2bf(ds * bf2f(v.w) + cs * bf2f(ov.w));
    *reinterpret_cast<ushort4*>(attb + (size_t)row * DD + d0) = o;
}

// ---------------------------------------------------------------------------
// K6: out = attb @ fcwb^T + fc_b, bf16 MFMA GEMM, register-pipelined.
// ---------------------------------------------------------------------------
__global__ __launch_bounds__(256) void out_kernel(
    const unsigned short* __restrict__ attb, const unsigned short* __restrict__ fcwb,
    const float* __restrict__ fc_b, float* __restrict__ out)
{
    const int ct = blockIdx.x;   // 0..15  col tile (64 cols)
    const int rt = blockIdx.y;   // 0..31  row tile (128 rows)
    const int t = threadIdx.x;
    const int w = t >> 6;
    const int lane = t & 63;
    const int n = lane & 15;
    const int quad = lane >> 4;

    const int row0 = rt * 128 + w * 32;
    const int col0 = ct * 64;

    const unsigned short* ap = attb + (size_t)(row0 + n) * DD + quad * 8;
    const unsigned short* bp = fcwb + (size_t)(col0 + n) * DD + quad * 8;

    f32x4 acc[2][4];
#pragma unroll
    for (int i = 0; i < 2; ++i)
#pragma unroll
        for (int j = 0; j < 4; ++j) acc[i][j] = (f32x4){0.f, 0.f, 0.f, 0.f};

    bf16x8 a[2][2], b[2][4];
    a[0][0] = ldfrag(ap);
    a[0][1] = ldfrag(ap + 16 * DD);
#pragma unroll
    for (int j = 0; j < 4; ++j) b[0][j] = ldfrag(bp + (size_t)(j * 16) * DD);

    int cur = 0;
    for (int kc = 0; kc < DD; kc += 32) {
        const int nxt = cur ^ 1;
        if (kc + 32 < DD) {
            a[nxt][0] = ldfrag(ap + kc + 32);
            a[nxt][1] = ldfrag(ap + 16 * DD + kc + 32);
#pragma unroll
            for (int j = 0; j < 4; ++j)
                b[nxt][j] = ldfrag(bp + (size_t)(j * 16) * DD + kc + 32);
        }
#pragma unroll
        for (int i = 0; i < 2; ++i)
#pragma unroll
            for (int j = 0; j < 4; ++j)
                acc[i][j] = MFMA16(a[cur][i], b[cur][j], acc[i][j], 0, 0, 0);
        cur = nxt;
    }

#pragma unroll
    for (int j = 0; j < 4; ++j) {
        const int col = col0 + j * 16 + n;
        const float bias = fc_b[col];
#pragma unroll
        for (int i = 0; i < 2; ++i)
#pragma unroll
            for (int r = 0; r < 4; ++r) {
                const int grow = row0 + i * 16 + quad * 4 + r;
                out[(size_t)grow * DD + col] = acc[i][j][r] + bias;
            }
    }
}

// ---------------------------------------------------------------------------
extern "C" void kernel_launch(void* const* d_in, const int* in_sizes, int n_in,
                              void* d_out, int out_size, void* d_ws, size_t ws_size,
                              hipStream_t stream) {
    const float* values = (const float*)d_in[0];
    const float* keys   = (const float*)d_in[1];
    const float* query  = (const float*)d_in[2];
    const float* ovals  = (const float*)d_in[3];
    const float* okeys  = (const float*)d_in[4];
    const float* Wv     = (const float*)d_in[5];
    const float* Wk     = (const float*)d_in[6];
    const float* Wq     = (const float*)d_in[7];
    const float* fc_w   = (const float*)d_in[8];
    const float* fc_b   = (const float*)d_in[9];
    // d_in[10]: mask — HIST==L makes it pure causal, handled analytically.
    float* out = (float*)d_out;

    float* ws      = (float*)d_ws;
    float* ediag   = ws;                     // 65536 f32
    float* Zbuf    = ediag + 65536;          // 65536 f32 (atomic accum)
    float* colsum  = Zbuf + 65536;           // 65536 f32 (atomic accum)
    float* invZ    = colsum + 65536;
    float* diag_s  = invZ + 65536;
    unsigned short* qb   = (unsigned short*)(diag_s + 65536);  // [32][2048][64] bf16
    unsigned short* okb  = qb   + 4194304;
    unsigned short* vb   = okb  + 4194304;   // [n][l][1024] bf16
    unsigned short* ovb  = vb   + 4194304;
    unsigned short* attb = ovb  + 4194304;   // [4096][1024] bf16
    unsigned short* fcwb = attb + 4194304;   // [1024][1024] bf16
    unsigned short* wfrag = fcwb + 1048576;  // 3*8*64*8 = 12288 bf16 (24 KB)

    // zero the two atomic accumulators (Zbuf, colsum are adjacent)
    hipMemsetAsync(Zbuf, 0, 2 * 65536 * sizeof(float), stream);

    wcvt_kernel<<<dim3(6), 256, 0, stream>>>(Wk, Wq, Wv, wfrag);
    fcw_kernel<<<dim3(1024), 256, 0, stream>>>(fc_w, fcwb);
    proj_kernel<<<dim3(64, 16, 2), 256, 0, stream>>>(
        values, keys, query, ovals, okeys, wfrag, qb, okb, vb, ovb, ediag);
    zrow_part<<<dim3(64, NHH), 256, 0, stream>>>(qb, okb, Zbuf);
    zfin_kernel<<<dim3(256), 256, 0, stream>>>(Zbuf, ediag, invZ, diag_s);
    colsum_part<<<dim3(64, NHH), 256, 0, stream>>>(qb, okb, invZ, colsum);
    att_kernel<<<dim3(NB * LL), 256, 0, stream>>>(vb, ovb, diag_s, colsum, attb);
    out_kernel<<<dim3(16, 32), 256, 0, stream>>>(attb, fcwb, fc_b, out);
}